// Round 12
// baseline (1525.704 us; speedup 1.0000x reference)
//
#include <hip/hip_runtime.h>

#define NN 1024
#define MM 1024
#define NB 16
#define BIGF 1.0e10f
#define TP 17                       // tile pad
#define NW 8                        // fwd: waves per workgroup
#define OFS 5                       // fwd: interval offset between waves
#define CW 16                       // fwd: steps per interval
#define NA 68                       // fwd: active intervals per wave
#define NGI (OFS * (NW - 1) + NA)   // fwd: 103 global intervals

typedef float f32x4 __attribute__((ext_vector_type(4)));

// softmin3 with the always-one term elided: one of exp(mn-*) is exp(0)=1.
__device__ __forceinline__ float softmin3f(float a, float b, float c) {
  const float mn = fminf(a, fminf(b, c));
  const float mx = fmaxf(a, fmaxf(b, c));
  const float md = __builtin_amdgcn_fmed3f(a, b, c);
  const float s = 1.0f + __expf(mn - md) + __expf(mn - mx);
  return mn - __logf(s);
}

// D[b,i,j] = (x[b,i] - y[j])^2 ; coalesced float4 writes
__global__ __launch_bounds__(256) void d_init_kernel(const float* __restrict__ x,
                                                     const float* __restrict__ y,
                                                     float* __restrict__ D) {
  size_t idx = ((size_t)blockIdx.x * blockDim.x + threadIdx.x) * 4;
  int j = (int)(idx & (MM - 1));
  size_t bi = idx >> 10;
  float xi = x[bi];
  const float4 yv = *reinterpret_cast<const float4*>(y + j);
  float t0 = xi - yv.x, t1 = xi - yv.y, t2 = xi - yv.z, t3 = xi - yv.w;
  float4 o;
  o.x = t0 * t0; o.y = t1 * t1; o.z = t2 * t2; o.w = t3 * t3;
  *reinterpret_cast<float4*>(D + idx) = o;
}

// R boundary: R[b,0,0]=0, R[b,0,j>=1]=BIG, R[b,i>=1,0]=BIG
__global__ __launch_bounds__(1024) void r_bound_kernel(float* __restrict__ R) {
  int b = blockIdx.x, t = threadIdx.x;
  float* Rb = R + (size_t)b * (NN + 1) * (MM + 1);
  Rb[t + 1] = BIGF;
  Rb[(size_t)(t + 1) * (MM + 1)] = BIGF;
  if (t == 0) Rb[0] = 0.0f;
}

// ---------------- forward (round-11, measured best ~545us) ------------------
__global__ __launch_bounds__(512) void sdtw_fwd(const float* __restrict__ x,
                                                const float* __restrict__ y,
                                                float* __restrict__ R,
                                                float* __restrict__ score) {
  __shared__ float ypad[1152];  // ypad[k] = y[k-64], zeros outside
  __shared__ float tile[NW][2112];
  __shared__ float ringR[NW][128];
  const int b = blockIdx.x, t = threadIdx.x;
  const int w = t >> 6, l = t & 63;
  float* __restrict__ Rb = R + (size_t)b * (NN + 1) * (MM + 1);
  for (int k = t; k < 1152; k += 512)
    ypad[k] = (k >= 64 && k < 64 + MM) ? y[k - 64] : 0.0f;
  const int i1 = 128 * w + 2 * l + 1;
  const float x1 = x[b * NN + i1 - 1];
  const float x2 = x[b * NN + i1];
  float* tl = &tile[w][33 * l];
  const int wm1 = (w > 0) ? (w - 1) : 0;
  const bool L0 = (l == 0), W0 = (w == 0);
  const bool pub = (l == 63) && (w < NW - 1);
  float c1 = BIGF, c2 = BIGF, m1 = BIGF, m2 = BIGF, ringPrev = BIGF;
  __syncthreads();
  for (int G = 0; G < NGI; ++G) {
    const int a = G - OFS * w;
    if (a >= 0 && a < NA) {
      const int s0 = a * CW;
#pragma unroll 4
      for (int p = 0; p < CW; ++p) {
        const int s = s0 + p;
        const int j = s - l;
        const bool act = (j >= 1) && (j <= MM);
        float up = __shfl_up(m1, 1);   // R(i1-1, j)
        float dg = __shfl_up(m2, 1);   // R(i1-1, j-1)
        const float rc = ringR[wm1][j & 127];
        if (L0) {
          up = W0 ? BIGF : rc;
          dg = W0 ? ((j == 1) ? 0.0f : BIGF) : ringPrev;
        }
        ringPrev = act ? rc : ringPrev;
        const float yv = ypad[j + 63];  // y[j-1]; pad-zero when inactive
        float dv1 = x1 - yv; dv1 *= dv1;
        const float r1 = dv1 + softmin3f(dg, up, c1);
        float dv2 = x2 - yv; dv2 *= dv2;
        const float r2 = dv2 + softmin3f(c1, r1, c2);
        tl[p] = r1;
        tl[16 + p] = r2;
        if (pub && act) ringR[w][j & 127] = r2;
        m2 = act ? m1 : m2;
        m1 = act ? r2 : m1;
        c1 = act ? r1 : c1;
        c2 = act ? r2 : c2;
      }
      __builtin_amdgcn_wave_barrier();
#pragma unroll
      for (int g = 0; g < 32; ++g) {
        const int rr = 4 * g + (l >> 4);
        const int sl = l & 15;
        const int col = s0 + sl - (rr >> 1);
        const float v = tile[w][rr * 16 + (rr >> 1) + sl];
        if (col >= 1 && col <= MM)
          Rb[(size_t)(128 * w + 1 + rr) * (MM + 1) + col] = v;
      }
    }
    __syncthreads();
  }
  if (w == NW - 1 && l == 63) score[b] = m1;  // R[1024][1024]
}

// ---------------- backward: 512 threads, 2 consecutive rows/thread ----------
// Thread t owns i1=2t+1 (tile tE[t]) and i2=2t+2 (tO[t]). Register deps:
// i1.dn = own i2 (pE2/pR2); both rt = own carries; i1.dg = own i2 two diags
// back (gE1/gR1). Cross-thread: i2.dn = thread t+1's i1 via parity exch
// (eex/rex); i2.dg = carry of previous exch read (gE2/gR2). Shared D-term:
// D(i1+1,j1) == D(i2,j2+1) (B). All invalid paths carry (E=0, R=-BIG) so exp
// terms underflow to 0; garbage reaches only tile slots the coop bounds-check
// discards.
__global__ __launch_bounds__(512) void sdtw_bwd(const float* __restrict__ x,
                                                const float* __restrict__ y,
                                                const float* __restrict__ R,
                                                float* __restrict__ E) {
  __shared__ float ypad[3088];     // ypad[k] = y[k-1025], zeros outside
  __shared__ float tE[512][TP];    // output row 2k   (i = 2k+1)
  __shared__ float tO[512][TP];    // output row 2k+1 (i = 2k+2)
  __shared__ float eex[2][513];    // parity exch: thread k's i1-row E
  __shared__ float rex[2][513];    // parity exch: thread k's i1-row R
  const int b = blockIdx.x, t = threadIdx.x;
  const float* __restrict__ Rb = R + (size_t)b * (NN + 1) * (MM + 1);
  float* __restrict__ Eb = E + (size_t)b * (size_t)NN * MM;
  for (int k = t; k < 3088; k += 512)
    ypad[k] = (k >= 1025 && k < 1025 + MM) ? y[k - 1025] : 0.0f;
  for (int k = t; k < 513; k += 512) {
    eex[0][k] = 0.0f; eex[1][k] = 0.0f;
    rex[0][k] = -BIGF; rex[1][k] = -BIGF;
  }
  const int i1 = 2 * t + 1, i2 = 2 * t + 2;
  const float xa = x[b * NN + 2 * t];                   // x(i1)
  const float xb = x[b * NN + 2 * t + 1];               // x(i2)
  const float xc = x[b * NN + min(NN - 1, 2 * t + 2)];  // x(i2+1), clamped
  const bool seedthr = (t == 511);
  float pE1 = 0.f, pR1 = -BIGF;  // i1 @ d+1
  float pE2 = 0.f, pR2 = -BIGF;  // i2 @ d+1
  float gE1 = 0.f, gR1 = -BIGF;  // i2 @ d+2
  float gE2 = 0.f, gR2 = -BIGF;  // (i2+1) @ d+2 (prev exch read)

  // coop load/store helpers (8 passes x 128 rows; parity-split tiles)
#define COOP_LOAD(D0N)                                                         \
  {                                                                            \
    _Pragma("unroll")                                                          \
    for (int pass = 0; pass < 8; ++pass) {                                     \
      const int row = (pass << 7) + (t >> 2);                                  \
      const int ir = row + 1;                                                  \
      const int c4 = (t & 3) << 2;                                             \
      const int jn = (D0N)-ir + c4;                                            \
      float* tp = (row & 1) ? &tO[row >> 1][0] : &tE[row >> 1][0];             \
      if (jn >= 1 && jn + 3 <= MM) {                                           \
        const float4 v =                                                       \
            *reinterpret_cast<const float4*>(Rb + (size_t)ir * (MM + 1) + jn); \
        tp[c4] = v.x; tp[c4 + 1] = v.y; tp[c4 + 2] = v.z; tp[c4 + 3] = v.w;    \
      } else {                                                                 \
        _Pragma("unroll")                                                      \
        for (int c = 0; c < 4; ++c) {                                          \
          const int jc = jn + c;                                               \
          tp[c4 + c] =                                                         \
              (jc >= 1 && jc <= MM) ? Rb[(size_t)ir * (MM + 1) + jc] : -BIGF;  \
        }                                                                      \
      }                                                                        \
    }                                                                          \
  }

  COOP_LOAD(128 << 4)
  __syncthreads();

  for (int K = 128; K >= 0; --K) {
    const int d0 = K << 4;
    // y rotation: at step s, ya = y[j1], yb = y[j1-1], yc = y[j1-2]
    float ya = ypad[d0 + 15 - i1 + 1025];
    float yb = ypad[d0 + 15 - i1 + 1024];
#pragma unroll
    for (int p = 0; p < 16; ++p) {
      const int s = 15 - p;
      const int d = d0 + s;
      const int j1 = d - i1;
      const int rp = (d & 1) ^ 1, wp = d & 1;
      const float yc = ypad[j1 + 1023];  // y[j1-2]; index >= 0 always
      const float nE = eex[rp][t + 1];   // (i2+1, j2) @ d+1
      const float nR = rex[rp][t + 1];
      const float r1v = tE[t][s];        // R(i1, j1)
      const float r2v = tO[t][s];        // R(i2, j2), j2 = j1-1
      float A = xc - yc; A *= A;  // D(i2+1, j2)
      float B = xb - yb; B *= B;  // D(i2, j2+1) == D(i1+1, j1)
      float C = xc - yb; C *= C;  // D(i2+1, j2+1)
      float F = xa - ya; F *= F;  // D(i1, j1+1)
      float G = xb - ya; G *= G;  // D(i1+1, j1+1)
      float e2 = nE * __expf(nR - r2v - A) + pE2 * __expf(pR2 - r2v - B) +
                 gE2 * __expf(gR2 - r2v - C);
      if (seedthr && d == 2048) e2 += 1.0f;  // seed at (N, M)
      float e1 = pE2 * __expf(pR2 - r1v - B) + pE1 * __expf(pR1 - r1v - F) +
                 gE1 * __expf(gR1 - r1v - G);
      tE[t][s] = e1;  // unmasked: coop bounds-check discards garbage
      tO[t][s] = e2;
      const bool act1 = (j1 >= 1) && (j1 <= MM);
      const bool act2 = (j1 >= 2) && (j1 <= MM + 1);  // j2 in [1, MM]
      eex[wp][t] = act1 ? e1 : 0.0f;
      rex[wp][t] = act1 ? r1v : -BIGF;
      gE2 = nE; gR2 = nR;
      gE1 = pE2; gR1 = pR2;
      pE2 = act2 ? e2 : 0.0f; pR2 = act2 ? r2v : -BIGF;
      pE1 = act1 ? e1 : 0.0f; pR1 = act1 ? r1v : -BIGF;
      ya = yb; yb = yc;
      __syncthreads();
    }
    // coop: store E window, then load R window K-1 into same slots
#pragma unroll
    for (int pass = 0; pass < 8; ++pass) {
      const int row = (pass << 7) + (t >> 2);
      const int ir = row + 1;
      const int c4 = (t & 3) << 2;
      const int jb2 = d0 - ir + c4;
      float* tp = (row & 1) ? &tO[row >> 1][0] : &tE[row >> 1][0];
      float fv[4];
#pragma unroll
      for (int c = 0; c < 4; ++c) fv[c] = tp[c4 + c];
      if (jb2 >= 1 && jb2 + 3 <= MM) {
        f32x4 v;
        v[0] = fv[0]; v[1] = fv[1]; v[2] = fv[2]; v[3] = fv[3];
        const float* pp = Eb + (size_t)row * MM + (jb2 - 1);
        asm volatile("global_store_dwordx4 %0, %1, off" ::"v"(pp), "v"(v) : "memory");
      } else if (jb2 + 3 >= 1 && jb2 <= MM) {
#pragma unroll
        for (int c = 0; c < 4; ++c) {
          const int jc = jb2 + c;
          if (jc >= 1 && jc <= MM) Eb[(size_t)row * MM + (jc - 1)] = fv[c];
        }
      }
      const int jn = jb2 - 16;
      if (jn >= 1 && jn + 3 <= MM) {
        const float4 v = *reinterpret_cast<const float4*>(Rb + (size_t)ir * (MM + 1) + jn);
        tp[c4] = v.x; tp[c4 + 1] = v.y; tp[c4 + 2] = v.z; tp[c4 + 3] = v.w;
      } else {
#pragma unroll
        for (int c = 0; c < 4; ++c) {
          const int jc = jn + c;
          tp[c4 + c] = (jc >= 1 && jc <= MM) ? Rb[(size_t)ir * (MM + 1) + jc] : -BIGF;
        }
      }
    }
    __syncthreads();
  }
#undef COOP_LOAD
}

extern "C" void kernel_launch(void* const* d_in, const int* in_sizes, int n_in,
                              void* d_out, int out_size, void* d_ws, size_t ws_size,
                              hipStream_t stream) {
  const float* x = (const float*)d_in[0];  // [16, 1024]
  const float* y = (const float*)d_in[1];  // [1024]
  float* out = (float*)d_out;
  float* score = out;                               // [16]
  float* D = out + NB;                              // [16,1024,1024]
  float* R = D + (size_t)NB * NN * MM;              // [16,1025,1025]
  float* E = R + (size_t)NB * (NN + 1) * (MM + 1);  // [16,1024,1024]

  hipLaunchKernelGGL(d_init_kernel, dim3((NB * NN * MM) / (256 * 4)), dim3(256), 0, stream,
                     x, y, D);
  hipLaunchKernelGGL(r_bound_kernel, dim3(NB), dim3(1024), 0, stream, R);
  hipLaunchKernelGGL(sdtw_fwd, dim3(NB), dim3(512), 0, stream, x, y, R, score);
  hipLaunchKernelGGL(sdtw_bwd, dim3(NB), dim3(512), 0, stream, x, y, R, E);
}

// Round 13
// 1372.164 us; speedup vs baseline: 1.1119x; 1.1119x over previous
//
#include <hip/hip_runtime.h>

#define NN 1024
#define MM 1024
#define NB 16
#define BIGF 1.0e10f
#define TP 17                       // bwd tile pad
#define NW 8                        // fwd: waves per workgroup
#define OFS 5                       // fwd: interval offset between waves
#define CW 16                       // fwd: steps per interval
#define NA 68                       // fwd: active intervals per wave
#define NGI (OFS * (NW - 1) + NA)   // fwd: 103 global intervals

typedef float f32x4 __attribute__((ext_vector_type(4)));

// softmin3 with the always-one term elided: one of exp(mn-*) is exp(0)=1.
__device__ __forceinline__ float softmin3f(float a, float b, float c) {
  const float mn = fminf(a, fminf(b, c));
  const float mx = fmaxf(a, fmaxf(b, c));
  const float md = __builtin_amdgcn_fmed3f(a, b, c);
  const float s = 1.0f + __expf(mn - md) + __expf(mn - mx);
  return mn - __logf(s);
}

// D[b,i,j] = (x[b,i] - y[j])^2 ; coalesced float4 writes
__global__ __launch_bounds__(256) void d_init_kernel(const float* __restrict__ x,
                                                     const float* __restrict__ y,
                                                     float* __restrict__ D) {
  size_t idx = ((size_t)blockIdx.x * blockDim.x + threadIdx.x) * 4;
  int j = (int)(idx & (MM - 1));
  size_t bi = idx >> 10;
  float xi = x[bi];
  const float4 yv = *reinterpret_cast<const float4*>(y + j);
  float t0 = xi - yv.x, t1 = xi - yv.y, t2 = xi - yv.z, t3 = xi - yv.w;
  float4 o;
  o.x = t0 * t0; o.y = t1 * t1; o.z = t2 * t2; o.w = t3 * t3;
  *reinterpret_cast<float4*>(D + idx) = o;
}

// R boundary: R[b,0,0]=0, R[b,0,j>=1]=BIG, R[b,i>=1,0]=BIG
__global__ __launch_bounds__(1024) void r_bound_kernel(float* __restrict__ R) {
  int b = blockIdx.x, t = threadIdx.x;
  float* Rb = R + (size_t)b * (NN + 1) * (MM + 1);
  Rb[t + 1] = BIGF;
  Rb[(size_t)(t + 1) * (MM + 1)] = BIGF;
  if (t == 0) Rb[0] = 0.0f;
}

// ---------------- forward (round-7 fwd, measured best ~478us) ---------------
// Wave w owns rows 128w+1..128w+128; lane l owns i1=128w+2l+1, i2=i1+1.
// Lane l at step s computes col j = s - l. ONE shuffle per step (up); the
// diag value is the previous step's raw shuffle result (carry identity).
// y + boundary ring hoisted into registers per interval (off-chain).
__global__ __launch_bounds__(512) void sdtw_fwd(const float* __restrict__ x,
                                                const float* __restrict__ y,
                                                float* __restrict__ R,
                                                float* __restrict__ score) {
  __shared__ float tile[NW][2112];
  __shared__ float ringR[NW][128];
  const int b = blockIdx.x, t = threadIdx.x;
  const int w = t >> 6, l = t & 63;
  float* __restrict__ Rb = R + (size_t)b * (NN + 1) * (MM + 1);
  const int i1 = 128 * w + 2 * l + 1;
  const float x1 = x[b * NN + i1 - 1];
  const float x2 = x[b * NN + i1];
  float* tl = &tile[w][33 * l];
  const int wm1 = (w > 0) ? (w - 1) : 0;
  const bool L0 = (l == 0), W0 = (w == 0);
  const bool pub = (l == 63) && (w < NW - 1);
  float c1 = BIGF, c2 = BIGF, m1 = BIGF;
  float dgc = BIGF;  // carry: raw up-shuffle of previous step
  __syncthreads();
  for (int G = 0; G < NGI; ++G) {
    const int a = G - OFS * w;
    if (a >= 0 && a < NA) {
      const int s0 = a * CW;
      // hoisted inputs: y (global, L1-resident) + boundary ring (uniform LDS)
      float yw[16], rgm[17];
#pragma unroll
      for (int p = 0; p < 16; ++p) {
        const int jy = s0 + p - l - 1;
        yw[p] = y[(jy >= 0 && jy < MM) ? jy : 0];
      }
#pragma unroll
      for (int k = 0; k < 17; ++k) rgm[k] = ringR[wm1][(s0 + k - 1) & 127];
#pragma unroll
      for (int p = 0; p < CW; ++p) {
        const int j = s0 + p - l;
        const bool act = (j >= 1) && (j <= MM);
        const float up_raw = __shfl_up(m1, 1);  // R(i1-1, j)
        float up = up_raw;
        float dg = dgc;                          // R(i1-1, j-1) carry
        if (L0) {
          up = W0 ? BIGF : rgm[p + 1];
          dg = W0 ? ((j == 1) ? 0.0f : BIGF) : ((j == 1) ? BIGF : rgm[p]);
        }
        dgc = up_raw;
        const float yv = yw[p];
        float dv1 = x1 - yv; dv1 *= dv1;
        const float r1 = dv1 + softmin3f(dg, up, c1);
        float dv2 = x2 - yv; dv2 *= dv2;
        const float r2 = dv2 + softmin3f(c1, r1, c2);
        tl[p] = r1;
        tl[16 + p] = r2;
        if (pub && act) ringR[w][j & 127] = r2;
        m1 = act ? r2 : m1;
        c1 = act ? r1 : c1;
        c2 = act ? r2 : c2;
      }
      __builtin_amdgcn_wave_barrier();
      // cooperative coalesced store of window a (own wave's tile only)
#pragma unroll
      for (int g = 0; g < 32; ++g) {
        const int rr = 4 * g + (l >> 4);
        const int sl = l & 15;
        const int col = s0 + sl - (rr >> 1);
        const float v = tile[w][rr * 16 + (rr >> 1) + sl];
        if (col >= 1 && col <= MM)
          Rb[(size_t)(128 * w + 1 + rr) * (MM + 1) + col] = v;
      }
    }
    __syncthreads();
  }
  if (w == NW - 1 && l == 63) score[b] = m1;  // R[1024][1024]
}

// ---------------- backward (round-11, measured best 846us) ------------------
__global__ __launch_bounds__(1024) void sdtw_bwd(const float* __restrict__ x,
                                                 const float* __restrict__ y,
                                                 const float* __restrict__ R,
                                                 float* __restrict__ E) {
  __shared__ float ypad[3088];  // ypad[k] = y[k-1025], zeros outside
  __shared__ float rbx[4][NN + 2];
  __shared__ float ebx[4][NN + 2];
  __shared__ float tile[NN][TP];
  const int b = blockIdx.x, t = threadIdx.x;
  const int i = t + 1;
  const float* __restrict__ Rb = R + (size_t)b * (NN + 1) * (MM + 1);
  float* __restrict__ Eb = E + (size_t)b * (size_t)NN * MM;
  for (int k = t; k < 3088; k += 1024)
    ypad[k] = (k >= 1025 && k < 1025 + MM) ? y[k - 1025] : 0.0f;
#pragma unroll
  for (int q = 0; q < 4; ++q) { rbx[q][i] = -BIGF; ebx[q][i] = 0.0f; }
  if (t == NN - 1) {
#pragma unroll
    for (int q = 0; q < 4; ++q) { rbx[q][NN + 1] = -BIGF; ebx[q][NN + 1] = 0.0f; }
  }
  const float xi = x[b * NN + t];                              // X(i)
  const float xi1 = x[b * NN + ((t + 1 < NN) ? (t + 1) : t)];  // X(i+1)
  const bool seedrow = (i == NN);
  float rt_e = 0.0f, rt_r = -BIGF;    // (i, j+1) carries
  float dgn_e = 0.0f, dgn_r = -BIGF;  // (i+1, j+1) carries
  // prologue: coop-load R tile for block K=128
#pragma unroll
  for (int pass = 0; pass < 4; ++pass) {
    const int row = (pass << 8) + (t >> 2);
    const int ir = row + 1;
    const int c4 = (t & 3) << 2;
    const int jb2 = (128 << 4) - ir + c4;
    if (jb2 >= 1 && jb2 + 3 <= MM) {
      const float4 v = *reinterpret_cast<const float4*>(Rb + (size_t)ir * (MM + 1) + jb2);
      tile[row][c4] = v.x; tile[row][c4 + 1] = v.y;
      tile[row][c4 + 2] = v.z; tile[row][c4 + 3] = v.w;
    } else {
#pragma unroll
      for (int c = 0; c < 4; ++c) {
        const int jc = jb2 + c;
        tile[row][c4 + c] =
            (jc >= 1 && jc <= MM) ? Rb[(size_t)ir * (MM + 1) + jc] : -BIGF;
      }
    }
  }
  __syncthreads();
  float yj = ypad[3088 - i];  // y[j] seed at d=2063 (j = 2063 - i)

  for (int K = 128; K >= 0; --K) {
    const int d0 = K << 4;
#pragma unroll
    for (int p = 0; p < 16; ++p) {
      const int s = 15 - p;  // descending d within block
      const int d = d0 + s;
      const int j = d - i;
      const bool act = (j >= 1) && (j <= MM);
      const float dn_r = rbx[(s + 1) & 3][i + 1];  // (i+1, j) at diag d+1
      const float dn_e = ebx[(s + 1) & 3][i + 1];
      const float yjm1 = ypad[j + 1024];           // y[j-1], pad-zero outside
      const float rij = tile[t][s];
      float d1 = xi1 - yjm1; d1 *= d1;  // D(i+1, j)
      float d2 = xi - yj;    d2 *= d2;  // D(i,   j+1)
      float d3 = xi1 - yj;   d3 *= d3;  // D(i+1, j+1)
      const float a1 = dn_r - rij - d1;
      const float a2 = rt_r - rij - d2;
      const float a3 = dgn_r - rij - d3;
      float acc = dn_e * __expf(a1) + rt_e * __expf(a2) + dgn_e * __expf(a3);
      if (seedrow && j == MM) acc += 1.0f;
      rbx[s & 3][i] = act ? rij : -BIGF;
      ebx[s & 3][i] = act ? acc : 0.0f;
      tile[t][s] = act ? acc : 0.0f;  // in-place E
      rt_e = act ? acc : 0.0f;
      rt_r = act ? rij : -BIGF;
      dgn_e = dn_e; dgn_r = dn_r;
      yj = yjm1;
      __syncthreads();
    }
    // coop: store E tile, then load R tile for block K-1 into same slots
#pragma unroll
    for (int pass = 0; pass < 4; ++pass) {
      const int row = (pass << 8) + (t >> 2);
      const int ir = row + 1;
      const int c4 = (t & 3) << 2;
      const int jb2 = d0 - ir + c4;
      float fv[4];
#pragma unroll
      for (int c = 0; c < 4; ++c) fv[c] = tile[row][c4 + c];
      if (jb2 >= 1 && jb2 + 3 <= MM) {
        f32x4 v;
        v[0] = fv[0]; v[1] = fv[1]; v[2] = fv[2]; v[3] = fv[3];
        const float* pp = Eb + (size_t)row * MM + (jb2 - 1);
        asm volatile("global_store_dwordx4 %0, %1, off" ::"v"(pp), "v"(v) : "memory");
      } else if (jb2 + 3 >= 1 && jb2 <= MM) {
#pragma unroll
        for (int c = 0; c < 4; ++c) {
          const int jc = jb2 + c;
          if (jc >= 1 && jc <= MM) Eb[(size_t)row * MM + (jc - 1)] = fv[c];
        }
      }
      const int jn = jb2 - 16;  // next block window
      if (jn >= 1 && jn + 3 <= MM) {
        const float4 v = *reinterpret_cast<const float4*>(Rb + (size_t)ir * (MM + 1) + jn);
        tile[row][c4] = v.x; tile[row][c4 + 1] = v.y;
        tile[row][c4 + 2] = v.z; tile[row][c4 + 3] = v.w;
      } else {
#pragma unroll
        for (int c = 0; c < 4; ++c) {
          const int jc = jn + c;
          tile[row][c4 + c] =
              (jc >= 1 && jc <= MM) ? Rb[(size_t)ir * (MM + 1) + jc] : -BIGF;
        }
      }
    }
    __syncthreads();
  }
}

extern "C" void kernel_launch(void* const* d_in, const int* in_sizes, int n_in,
                              void* d_out, int out_size, void* d_ws, size_t ws_size,
                              hipStream_t stream) {
  const float* x = (const float*)d_in[0];  // [16, 1024]
  const float* y = (const float*)d_in[1];  // [1024]
  float* out = (float*)d_out;
  float* score = out;                               // [16]
  float* D = out + NB;                              // [16,1024,1024]
  float* R = D + (size_t)NB * NN * MM;              // [16,1025,1025]
  float* E = R + (size_t)NB * (NN + 1) * (MM + 1);  // [16,1024,1024]

  hipLaunchKernelGGL(d_init_kernel, dim3((NB * NN * MM) / (256 * 4)), dim3(256), 0, stream,
                     x, y, D);
  hipLaunchKernelGGL(r_bound_kernel, dim3(NB), dim3(1024), 0, stream, R);
  hipLaunchKernelGGL(sdtw_fwd, dim3(NB), dim3(512), 0, stream, x, y, R, score);
  hipLaunchKernelGGL(sdtw_bwd, dim3(NB), dim3(1024), 0, stream, x, y, R, E);
}